// Round 6
// baseline (511.405 us; speedup 1.0000x reference)
//
#include <hip/hip_runtime.h>
#include <hip/hip_bf16.h>
#include <math.h>

#define TB 4
#define TT 4096
#define HH 2048
#define DD 256
#define NN 32768
#define HQ 512
#define MM (TB*TT)

typedef __attribute__((ext_vector_type(8))) short bf16x8;
typedef __attribute__((ext_vector_type(8))) _Float16 f16x8;
typedef __attribute__((ext_vector_type(4))) float f32x4;

__device__ inline unsigned short f2bf(float x){
  __hip_bfloat16 h = __float2bfloat16(x);
  return *reinterpret_cast<unsigned short*>(&h);
}

__device__ inline unsigned short f2h(float x){
  _Float16 h = (_Float16)x;
  unsigned short u; __builtin_memcpy(&u, &h, 2); return u;
}

__device__ inline bf16x8 as_bf16x8(uint4 u){ bf16x8 r; __builtin_memcpy(&r,&u,16); return r; }

// async global->LDS DMA, 16B per lane. LDS dest = wave-uniform base + lane*16.
__device__ __forceinline__ void gload_ldsv(const void* g, void* l){
  __builtin_amdgcn_global_load_lds(
      (const __attribute__((address_space(1))) unsigned int*)g,
      (__attribute__((address_space(3))) unsigned int*)l, 16, 0, 0);
}

// K_prep: fused preprocessing — batch-mean (8192 blocks) + cvt_w (1024) +
// cvt_wobs (512) + beliefs-normalize (8192) + z1/z2/flag zeroing (129).
// (any-active moved to k_obs: flag must be zeroed in an EARLIER kernel.)
#define PREP_MEAN 8192
#define PREP_CVTW 1024
#define PREP_WOBS 512
#define PREP_BEL  8192
#define PREP_ZERO 129
#define PREP_GRID (PREP_MEAN+PREP_CVTW+PREP_WOBS+PREP_BEL+PREP_ZERO)
__global__ __launch_bounds__(256) void k_prep(
    const float* __restrict__ h, unsigned short* __restrict__ hmb,
    const float* __restrict__ Wg1, const float* __restrict__ Wp1,
    unsigned short* __restrict__ Wsw,
    const float* __restrict__ Wobs, unsigned short* __restrict__ wob,
    const float* __restrict__ bel, unsigned short* __restrict__ bbf,
    unsigned int* __restrict__ zbase){
  const int b = blockIdx.x;
  if (b < PREP_MEAN){
    const size_t i = (size_t)b*256 + threadIdx.x;
    const size_t TH4 = (size_t)TT*HH/4;
    const float4* p = (const float4*)h;
    float4 v0 = p[i], v1 = p[i+TH4], v2 = p[i+2*TH4], v3 = p[i+3*TH4];
    float4 m;
    m.x = 0.25f*(v0.x+v1.x+v2.x+v3.x);
    m.y = 0.25f*(v0.y+v1.y+v2.y+v3.y);
    m.z = 0.25f*(v0.z+v1.z+v2.z+v3.z);
    m.w = 0.25f*(v0.w+v1.w+v2.w+v3.w);
    ushort4 o; o.x = f2bf(m.x); o.y = f2bf(m.y); o.z = f2bf(m.z); o.w = f2bf(m.w);
    *(ushort4*)(hmb + i*4) = o;
  } else if (b < PREP_MEAN + PREP_CVTW){
    const int id = (b - PREP_MEAN)*256 + threadIdx.x;
    const int n = id >> 8;
    const int cg = id & 255;
    const int k = cg*8;
    const int kc = cg >> 2;
    const int c8 = cg & 3;
    const float* src = (n < HQ) ? (Wg1 + (size_t)n*HH + k) : (Wp1 + (size_t)(n-HQ)*HH + k);
    float4 v0 = *(const float4*)src;
    float4 v1 = *(const float4*)(src + 4);
    unsigned short o[8] = {f2h(v0.x),f2h(v0.y),f2h(v0.z),f2h(v0.w),
                           f2h(v1.x),f2h(v1.y),f2h(v1.z),f2h(v1.w)};
    const int nb = n >> 8, r = n & 255;
    const int s = (r & 3) ^ ((r >> 2) & 3);
    unsigned short* dst = Wsw + ((size_t)(nb*64 + kc))*8192 + r*32 + ((c8 ^ s) << 3);
    __builtin_memcpy(dst, o, 16);
  } else if (b < PREP_MEAN + PREP_CVTW + PREP_WOBS){
    const int idx4 = (b - PREP_MEAN - PREP_CVTW)*256 + threadIdx.x;
    float4 v = *(const float4*)(Wobs + (size_t)idx4*4);
    ushort4 o; o.x = f2bf(v.x); o.y = f2bf(v.y); o.z = f2bf(v.z); o.w = f2bf(v.w);
    *(ushort4*)(wob + (size_t)idx4*4) = o;
  } else if (b < PREP_MEAN + PREP_CVTW + PREP_WOBS + PREP_BEL){
    const int bb = b - (PREP_MEAN + PREP_CVTW + PREP_WOBS);
    const int n = (bb*256 + threadIdx.x) >> 6;
    const int lane = threadIdx.x & 63;
    const float4 v = *(const float4*)(bel + (size_t)n*DD + lane*4);
    float s = v.x*v.x + v.y*v.y + v.z*v.z + v.w*v.w;
    #pragma unroll
    for (int m = 1; m < 64; m <<= 1) s += __shfl_xor(s, m);
    const float inv = 1.f / fmaxf(sqrtf(s), 1e-8f);
    ushort4 o;
    o.x = f2bf(v.x*inv); o.y = f2bf(v.y*inv); o.z = f2bf(v.z*inv); o.w = f2bf(v.w*inv);
    *(ushort4*)(bbf + (size_t)n*DD + lane*4) = o;
  } else {
    // zero z1 (65536B) + z2 (65536B) + flag (contiguous) = 32832 u32
    const int idx = (b - (PREP_MEAN + PREP_CVTW + PREP_WOBS + PREP_BEL))*256 + threadIdx.x;
    if (idx < 32832) zbase[idx] = 0;
  }
}

// K3: obs_mean GEMM + FUSED obs_fin epilogue. BM=64, BN=256 (full rows per
// block) so the normalize/gate/softplus math runs in-register — om buffer and
// the obs_fin dispatch are gone. Writes out0, out3, obf directly.
// Full-DMA double-buffer staging (r4 template). +128 trailing blocks do the
// any-active flag (flag zeroed in k_prep, stream-ordered).
__global__ __launch_bounds__(256) void k_obs(const unsigned short* __restrict__ A,
    const unsigned short* __restrict__ Bw,
    const float* __restrict__ z1, const float* __restrict__ z2,
    const float* __restrict__ bg2, const float* __restrict__ bp2,
    float* __restrict__ out0, float* __restrict__ out3,
    unsigned short* __restrict__ obf,
    const unsigned char* __restrict__ mask, int* __restrict__ flag){
  const int blk = blockIdx.x;
  const int tid = threadIdx.x;
  if (blk >= 64){   // any-active part
    const int i = (blk - 64)*256 + tid;
    const int any = (mask[i] != 0) ? 1 : 0;
    if (__ballot(any)){
      if ((tid & 63) == 0) atomicOr(flag, 1);
    }
    return;
  }
  const int m0 = blk*64;
  const int w = tid>>6, lane = tid&63, lr = lane&15, q = lane>>4;
  __shared__ __align__(16) unsigned short As[2][64*32];    // 2 x 4 KB
  __shared__ __align__(16) unsigned short Bs[2][256*32];   // 2 x 16 KB
  f32x4 acc[16] = {};
  const int srow = lane >> 2, sch = (lane & 3) ^ (srow & 3);
  const unsigned short* asrc = A + (size_t)(m0 + w*16 + srow)*HH + sch*8;

  gload_ldsv(asrc, &As[0][w*16*32]);
  #pragma unroll
  for (int i = 0; i < 4; i++){
    const unsigned short* bsrc = Bw + (size_t)((i*4 + w)*16 + srow)*HH + sch*8;
    gload_ldsv(bsrc, &Bs[0][(i*4 + w)*16*32]);
  }
  __syncthreads();
  const int px = (q ^ (lr & 3)) << 3;
  for (int t = 0; t < 64; t++){
    const int cur = t & 1;
    if (t < 63){
      const int ko = (t+1)*32;
      gload_ldsv(asrc + ko, &As[cur^1][w*16*32]);
      #pragma unroll
      for (int i = 0; i < 4; i++){
        const unsigned short* bsrc = Bw + (size_t)((i*4 + w)*16 + srow)*HH + ko + sch*8;
        gload_ldsv(bsrc, &Bs[cur^1][(i*4 + w)*16*32]);
      }
    }
    bf16x8 a = as_bf16x8(*(const uint4*)&As[cur][(w*16 + lr)*32 + px]);
    #pragma unroll
    for (int j = 0; j < 16; j++){
      bf16x8 bb = as_bf16x8(*(const uint4*)&Bs[cur][(j*16 + lr)*32 + px]);
      acc[j] = __builtin_amdgcn_mfma_f32_16x16x32_bf16(a, bb, acc[j], 0, 0, 0);
    }
    __syncthreads();
  }
  // fused obs_fin: rows t = m0 + w*16 + q*4 + r; cols j*16 + lr
  #pragma unroll
  for (int r = 0; r < 4; r++){
    const int t = m0 + w*16 + q*4 + r;
    float s2 = 0.f;
    #pragma unroll
    for (int j = 0; j < 16; j++) s2 += acc[j][r]*acc[j][r];
    #pragma unroll
    for (int mk = 1; mk < 16; mk <<= 1) s2 += __shfl_xor(s2, mk);
    const float nrm = sqrtf(s2);
    float p = 0.f;
    #pragma unroll
    for (int bb = 0; bb < TB; bb++){
      float a = z1[bb*TT + t] + bg2[0];
      float c = z2[bb*TT + t] + bp2[0];
      float gate = 1.f/(1.f + expf(-a));
      float sp = (c > 0.f) ? (c + log1pf(expf(-c))) : log1pf(expf(c));
      p += gate * sp;
    }
    const float pm = p * 0.25f;
    const float sc = pm / fmaxf(nrm, 1e-8f);
    float qq = 0.f;
    #pragma unroll
    for (int j = 0; j < 16; j++){
      float o = acc[j][r] * sc;
      out0[(size_t)t*DD + j*16 + lr] = o;
      qq += o*o;
    }
    #pragma unroll
    for (int mk = 1; mk < 16; mk <<= 1) qq += __shfl_xor(qq, mk);
    const float r2 = sqrtf(qq);
    const float inv2 = 1.f / fmaxf(r2, 1e-8f);
    #pragma unroll
    for (int j = 0; j < 16; j++){
      float o = acc[j][r] * sc;
      obf[(size_t)t*DD + j*16 + lr] = f2bf(o * inv2);
    }
    if (lr == 0) out3[t] = (r2 > 0.05f) ? 1.f : 0.f;
  }
}

// K4: gate/prec layer1 — r4 full-DMA structure. NEW: A-DMAs issued before
// W-DMAs (HBM latency > L2 latency); j-pair MFMA reorder so the hi->lo
// dependent pair on the same accumulator has a 3-instr gap instead of 1.
__global__ __launch_bounds__(256, 2) void k_gp(const float* __restrict__ A,
    const unsigned short* __restrict__ Wsw,
    const float* __restrict__ bg1, const float* __restrict__ bp1,
    const float* __restrict__ Wg2, const float* __restrict__ Wp2,
    float* __restrict__ z1, float* __restrict__ z2){
  const int bid = blockIdx.x;
  const int nb = (bid >> 3) & 3;
  const int my = (bid & 7) + ((bid >> 5) << 3);
  const int m0 = my*128;
  const int tid = threadIdx.x;
  const int w = tid>>6, lane = tid&63, lr = lane&15, q = lane>>4;
  __shared__ __align__(16) unsigned short Ws[2][8192];   // 2 x 16 KB W tiles
  __shared__ __align__(16) float As[2][4096];            // 2 x 16 KB A tiles
  f32x4 acc[2][16] = {};

  const unsigned short* wt = Wsw + (size_t)nb*64*8192 + w*2048 + lane*8;
  const int rpB = lr*32 + ((q ^ ((lr & 3) ^ ((lr >> 2) & 3))) << 3);
  const int sr8 = lane >> 3;
  const int sc  = (lane & 7) ^ sr8;
  const float* asrc = A + (size_t)(m0 + w*32 + sr8)*HH + sc*4;

  #pragma unroll
  for (int i = 0; i < 4; i++) gload_ldsv(asrc + (size_t)i*8*HH, &As[0][(w*32 + i*8)*32]);
  #pragma unroll
  for (int i = 0; i < 4; i++) gload_ldsv(wt + i*512, &Ws[0][w*2048 + i*512]);
  __syncthreads();

  for (int t = 0; t < 64; t++){
    const int cur = t & 1;
    if (t < 63){
      #pragma unroll
      for (int i = 0; i < 4; i++)
        gload_ldsv(asrc + (size_t)i*8*HH + (t+1)*32, &As[cur^1][(w*32 + i*8)*32]);
      #pragma unroll
      for (int i = 0; i < 4; i++)
        gload_ldsv(wt + (size_t)(t+1)*8192 + i*512, &Ws[cur^1][w*2048 + i*512]);
    }
    const float* At = As[cur];
    f16x8 ah[2], al[2];
    #pragma unroll
    for (int i = 0; i < 2; i++){
      const int tr = w*32 + i*16 + lr;
      const int pxx = lr & 7;
      float4 fa = *(const float4*)&At[tr*32 + (((2*q)   ^ pxx) << 2)];
      float4 fb = *(const float4*)&At[tr*32 + (((2*q+1) ^ pxx) << 2)];
      float av[8] = {fa.x,fa.y,fa.z,fa.w, fb.x,fb.y,fb.z,fb.w};
      #pragma unroll
      for (int e = 0; e < 8; e++){
        _Float16 h = (_Float16)av[e];
        ah[i][e] = h; al[i][e] = (_Float16)(av[e] - (float)h);
      }
    }
    const unsigned short* Wc = Ws[cur];
    __builtin_amdgcn_s_setprio(1);
    #pragma unroll
    for (int jp = 0; jp < 8; jp++){
      f16x8 b0, b1;
      __builtin_memcpy(&b0, Wc + (2*jp)*512 + rpB, 16);
      __builtin_memcpy(&b1, Wc + (2*jp+1)*512 + rpB, 16);
      acc[0][2*jp]   = __builtin_amdgcn_mfma_f32_16x16x32_f16(ah[0], b0, acc[0][2*jp],   0, 0, 0);
      acc[1][2*jp]   = __builtin_amdgcn_mfma_f32_16x16x32_f16(ah[1], b0, acc[1][2*jp],   0, 0, 0);
      acc[0][2*jp+1] = __builtin_amdgcn_mfma_f32_16x16x32_f16(ah[0], b1, acc[0][2*jp+1], 0, 0, 0);
      acc[1][2*jp+1] = __builtin_amdgcn_mfma_f32_16x16x32_f16(ah[1], b1, acc[1][2*jp+1], 0, 0, 0);
      acc[0][2*jp]   = __builtin_amdgcn_mfma_f32_16x16x32_f16(al[0], b0, acc[0][2*jp],   0, 0, 0);
      acc[1][2*jp]   = __builtin_amdgcn_mfma_f32_16x16x32_f16(al[1], b0, acc[1][2*jp],   0, 0, 0);
      acc[0][2*jp+1] = __builtin_amdgcn_mfma_f32_16x16x32_f16(al[0], b1, acc[0][2*jp+1], 0, 0, 0);
      acc[1][2*jp+1] = __builtin_amdgcn_mfma_f32_16x16x32_f16(al[1], b1, acc[1][2*jp+1], 0, 0, 0);
    }
    __builtin_amdgcn_s_setprio(0);
    __syncthreads();
  }

  const bool isP = (nb >= 2);
  const float* b1p = isP ? bp1 : bg1;
  const float* w2 = isP ? Wp2 : Wg2;
  float* zt = isP ? z2 : z1;
  const int nbl = nb*256 - (isP ? HQ : 0);
  float s[2][4] = {};
  #pragma unroll
  for (int j = 0; j < 16; j++){
    const int n = nbl + j*16 + lr;
    const float bb = b1p[n], ww = w2[n];
    #pragma unroll
    for (int i = 0; i < 2; i++)
      #pragma unroll
      for (int r = 0; r < 4; r++)
        s[i][r] += fmaxf(acc[i][j][r] + bb, 0.f) * ww;
  }
  #pragma unroll
  for (int mk = 1; mk < 16; mk <<= 1)
    #pragma unroll
    for (int i = 0; i < 2; i++)
      #pragma unroll
      for (int r = 0; r < 4; r++)
        s[i][r] += __shfl_xor(s[i][r], mk);
  if (lr == 0){
    #pragma unroll
    for (int i = 0; i < 2; i++)
      #pragma unroll
      for (int r = 0; r < 4; r++)
        atomicAdd(&zt[m0 + w*32 + i*16 + q*4 + r], s[i][r]);
  }
}

// K7: fused sims + masked max/argmax — unchanged from round 5 (control).
__global__ __launch_bounds__(256) void k_sims(const unsigned short* __restrict__ obf,
    const unsigned short* __restrict__ bbf, const unsigned char* __restrict__ mask,
    float* __restrict__ pmax, int* __restrict__ pidx){
  const int bid = blockIdx.x;                // 0..1023
  const int rest = bid >> 3;
  const int ns = (bid & 7) + ((rest >> 5) << 3);   // 0..31; xcd = ns&7
  const int t0 = (rest & 31) * 128;
  const int nbase0 = ns * (NN/32);           // 1024-row slice
  const int tid = threadIdx.x;
  const int w = tid >> 6, lane = tid & 63;
  const int lr = lane & 15, q = lane >> 4;
  __shared__ __align__(16) unsigned short bt[2][32*256];   // 2 x 16 KB
  __shared__ __align__(16) unsigned char am[1024];
  const int srow = lane >> 5;
  const int sp   = lane & 31;

  ((unsigned int*)am)[tid] = ((const unsigned int*)(mask + nbase0))[tid];

  #pragma unroll
  for (int i = 0; i < 4; i++){
    const int row = (i*4 + w)*2 + srow;
    const unsigned short* src = bbf + (size_t)(nbase0 + row)*DD + ((sp ^ (row & 31)) << 3);
    gload_ldsv(src, &bt[0][(i*4 + w)*512]);
  }
  bf16x8 afr[2][8];
  #pragma unroll
  for (int i = 0; i < 2; i++){
    const unsigned short* ap = obf + (size_t)(t0 + w*32 + i*16 + lr)*DD + q*8;
    #pragma unroll
    for (int ks = 0; ks < 8; ks++)
      afr[i][ks] = as_bf16x8(*(const uint4*)(ap + ks*32));
  }
  __syncthreads();

  float vmax[2][4] = {{-INFINITY,-INFINITY,-INFINITY,-INFINITY},
                      {-INFINITY,-INFINITY,-INFINITY,-INFINITY}};
  int   vidx[2][4] = {{-1,-1,-1,-1},{-1,-1,-1,-1}};
  int cur = 0;
  for (int it = 0; it < 32; it++){
    const int nl = it*32;
    if (it < 31){
      #pragma unroll
      for (int i = 0; i < 4; i++){
        const int row = (i*4 + w)*2 + srow;
        const unsigned short* src = bbf + (size_t)(nbase0 + nl + 32 + row)*DD + ((sp ^ (row & 31)) << 3);
        gload_ldsv(src, &bt[cur^1][(i*4 + w)*512]);
      }
    }
    const unsigned short* btc = bt[cur];
    #pragma unroll
    for (int sub = 0; sub < 2; sub++){
      const int rowi = sub*16 + lr;
      const bool act = (am[nl + rowi] != 0);
      const unsigned short* bp = btc + rowi*256;
      f32x4 acc[2] = {{0.f,0.f,0.f,0.f},{0.f,0.f,0.f,0.f}};
      __builtin_amdgcn_s_setprio(1);
      #pragma unroll
      for (int ks = 0; ks < 8; ks++){
        const int p = (q + ks*4) ^ rowi;
        bf16x8 bfr = as_bf16x8(*(const uint4*)(bp + (p & 31)*8));
        acc[0] = __builtin_amdgcn_mfma_f32_16x16x32_bf16(afr[0][ks], bfr, acc[0], 0, 0, 0);
        acc[1] = __builtin_amdgcn_mfma_f32_16x16x32_bf16(afr[1][ks], bfr, acc[1], 0, 0, 0);
      }
      __builtin_amdgcn_s_setprio(0);
      if (act){
        const int n = nbase0 + nl + rowi;
        #pragma unroll
        for (int i = 0; i < 2; i++)
          #pragma unroll
          for (int r = 0; r < 4; r++)
            if (acc[i][r] > vmax[i][r]){ vmax[i][r] = acc[i][r]; vidx[i][r] = n; }
      }
    }
    __syncthreads();
    cur ^= 1;
  }
  #pragma unroll
  for (int mk = 1; mk < 16; mk <<= 1){
    #pragma unroll
    for (int i = 0; i < 2; i++)
      #pragma unroll
      for (int r = 0; r < 4; r++){
        float om = __shfl_xor(vmax[i][r], mk);
        int   oi = __shfl_xor(vidx[i][r], mk);
        if (om > vmax[i][r] || (om == vmax[i][r] && (unsigned)oi < (unsigned)vidx[i][r])){
          vmax[i][r] = om; vidx[i][r] = oi;
        }
      }
  }
  if (lr == 0){
    #pragma unroll
    for (int i = 0; i < 2; i++)
      #pragma unroll
      for (int r = 0; r < 4; r++){
        const int t = t0 + w*32 + i*16 + q*4 + r;
        pmax[ns*TT + t] = vmax[i][r];
        pidx[ns*TT + t] = vidx[i][r];
      }
  }
}

// K8: combine n-splits + match logic (uses out3 as the meaningful flag; rad gone)
__global__ __launch_bounds__(256) void k_combine(const float* __restrict__ pmax,
    const int* __restrict__ pidx, const float* __restrict__ out3,
    const int* __restrict__ flag, float* __restrict__ out1, float* __restrict__ out2){
  const int t = blockIdx.x*256 + threadIdx.x;
  float best = -INFINITY; int bi = -1;
  #pragma unroll
  for (int s = 0; s < 32; s++){
    float m = pmax[s*TT + t];
    if (m > best){ best = m; bi = pidx[s*TT + t]; }
  }
  const bool anyA = (flag[0] != 0);
  const bool mf = out3[t] != 0.f;
  const bool matched = mf && anyA && (best > 0.5f);
  out1[t] = matched ? best : 0.f;
  out2[t] = matched ? (float)bi : -1.f;
}

extern "C" void kernel_launch(void* const* d_in, const int* in_sizes, int n_in,
                              void* d_out, int out_size, void* d_ws, size_t ws_size,
                              hipStream_t stream) {
  const float* hidden = (const float*)d_in[0];
  const float* beliefs = (const float*)d_in[1];
  const unsigned char* amask = (const unsigned char*)d_in[2];
  const float* W_obs = (const float*)d_in[3];
  const float* W_g1 = (const float*)d_in[4];
  const float* b_g1 = (const float*)d_in[5];
  const float* W_g2 = (const float*)d_in[6];
  const float* b_g2 = (const float*)d_in[7];
  const float* W_p1 = (const float*)d_in[8];
  const float* b_p1 = (const float*)d_in[9];
  const float* W_p2 = (const float*)d_in[10];
  const float* b_p2 = (const float*)d_in[11];

  char* ws = (char*)d_ws;
  const size_t HMB_OFF  = 0;                 // 16777216
  const size_t WSW_OFF  = 16777216;          // 4194304 (swizzled)
  const size_t WOB_OFF  = 20971520;          // 1048576
  const size_t Z1_OFF   = 26214400;          // 65536
  const size_t Z2_OFF   = 26279936;          // 65536
  const size_t FLAG_OFF = 26345472;          // 256  (contiguous with z1/z2 for zeroing)
  const size_t OBF_OFF  = 26362112;          // 2097152
  const size_t BBF_OFF  = 28459264;          // 16777216
  const size_t PMAX_OFF = 45236480;          // 524288
  const size_t PIDX_OFF = 45760768;          // 524288    end ~46.3 MB

  unsigned short* hmb = (unsigned short*)(ws + HMB_OFF);
  unsigned short* Wsw = (unsigned short*)(ws + WSW_OFF);
  unsigned short* wob = (unsigned short*)(ws + WOB_OFF);
  float* z1  = (float*)(ws + Z1_OFF);
  float* z2  = (float*)(ws + Z2_OFF);
  int*   flg = (int*)(ws + FLAG_OFF);
  unsigned short* obf = (unsigned short*)(ws + OBF_OFF);
  unsigned short* bbf = (unsigned short*)(ws + BBF_OFF);
  float* pmax = (float*)(ws + PMAX_OFF);
  int*   pidx = (int*)(ws + PIDX_OFF);

  float* out0 = (float*)d_out;            // [T,D] obs_beliefs
  float* out1 = out0 + (size_t)TT*DD;     // [T] sims_out
  float* out2 = out1 + TT;                // [T] slots
  float* out3 = out2 + TT;                // [T] meaningful

  k_prep    <<<PREP_GRID, 256, 0, stream>>>(hidden, hmb, W_g1, W_p1, Wsw,
                W_obs, wob, beliefs, bbf, (unsigned int*)z1);
  k_gp      <<<512, 256, 0, stream>>>(hidden, Wsw, b_g1, b_p1, W_g2, W_p2, z1, z2);
  k_obs     <<<64 + NN/256, 256, 0, stream>>>(hmb, wob, z1, z2, b_g2, b_p2,
                out0, out3, obf, amask, flg);
  k_sims    <<<1024, 256, 0, stream>>>(obf, bbf, amask, pmax, pidx);
  k_combine <<<TT/256, 256, 0, stream>>>(pmax, pidx, out3, flg, out1, out2);
}